// Round 4
// baseline (377.276 us; speedup 1.0000x reference)
//
#include <hip/hip_runtime.h>

typedef unsigned short u16;
typedef unsigned int u32;
typedef short v8s __attribute__((ext_vector_type(8)));
typedef float v4f __attribute__((ext_vector_type(4)));

#define MFMA16(a, b, c) __builtin_amdgcn_mfma_f32_16x16x32_bf16((a), (b), (c), 0, 0, 0)

static __device__ __forceinline__ u16 f2bf(float f) {
    u32 u = __float_as_uint(f);
    u += 0x7fffu + ((u >> 16) & 1u);   // RNE
    return (u16)(u >> 16);
}

// async global->LDS, 16B per lane. LDS dest must be wave-uniform base + lane*16.
static __device__ __forceinline__ void gl2lds(const u16* g, u16* l) {
    __builtin_amdgcn_global_load_lds(
        (const __attribute__((address_space(1))) void*)g,
        (__attribute__((address_space(3))) void*)l, 16, 0, 0);
}

// ---------------------------------------------------------------------------
// prep: fp32 weights -> bf16 (Wqkv packed [1536][512], Wp [512][512]), bias pack
// ---------------------------------------------------------------------------
__global__ __launch_bounds__(256) void prep_kernel(
    const float* __restrict__ wq, const float* __restrict__ wk,
    const float* __restrict__ wv, const float* __restrict__ wp,
    const float* __restrict__ bq, const float* __restrict__ bk,
    const float* __restrict__ bv,
    u16* __restrict__ Wqkv, u16* __restrict__ Wp, float* __restrict__ bqkv) {
    int id = blockIdx.x * 256 + threadIdx.x;   // 0 .. 1048575
    float v;
    if (id < 262144)       v = wq[id];
    else if (id < 524288)  v = wk[id - 262144];
    else if (id < 786432)  v = wv[id - 524288];
    else                   v = wp[id - 786432];
    if (id < 786432) Wqkv[id] = f2bf(v);
    else             Wp[id - 786432] = f2bf(v);
    if (id < 1536) {
        float b = (id < 512) ? bq[id] : (id < 1024 ? bk[id - 512] : bv[id - 1024]);
        bqkv[id] = b;
    }
}

// ---------------------------------------------------------------------------
// GroupNorm pass 1: per (b,g) mean & rsigma over 16 ch x 1024 spatial
// ---------------------------------------------------------------------------
__global__ __launch_bounds__(256) void gn_stats(const float* __restrict__ x,
                                                float2* __restrict__ stats) {
    int g = blockIdx.x, b = blockIdx.y;
    const float4* x4 = (const float4*)x + (size_t)(b * 512 + g * 16) * 256;
    float s = 0.f, s2 = 0.f;
    for (int i = threadIdx.x; i < 4096; i += 256) {
        float4 v = x4[i];
        s  += v.x + v.y + v.z + v.w;
        s2 += v.x * v.x + v.y * v.y + v.z * v.z + v.w * v.w;
    }
    #pragma unroll
    for (int d = 1; d < 64; d <<= 1) { s += __shfl_xor(s, d); s2 += __shfl_xor(s2, d); }
    __shared__ float red1[4], red2[4];
    int w = threadIdx.x >> 6;
    if ((threadIdx.x & 63) == 0) { red1[w] = s; red2[w] = s2; }
    __syncthreads();
    if (threadIdx.x == 0) {
        s = red1[0] + red1[1] + red1[2] + red1[3];
        s2 = red2[0] + red2[1] + red2[2] + red2[3];
        float mu = s * (1.0f / 16384.0f);
        float var = s2 * (1.0f / 16384.0f) - mu * mu;
        stats[b * 32 + g] = make_float2(mu, rsqrtf(var + 1e-5f));
    }
}

// ---------------------------------------------------------------------------
// GroupNorm pass 2 + transpose: x[b,c,s] fp32 -> h[b*1024+s][c] bf16 (token-major)
// ---------------------------------------------------------------------------
__global__ __launch_bounds__(256) void gn_apply(
    const float* __restrict__ x, const float2* __restrict__ stats,
    const float* __restrict__ gnw, const float* __restrict__ gnb,
    u16* __restrict__ h) {
    int st = blockIdx.x, b = blockIdx.y;
    int s0 = st * 64;
    __shared__ float smu[32], srs[32], sw[512], sbv[512];
    __shared__ alignas(16) u16 hs[64][520];
    int t = threadIdx.x;
    if (t < 32) { float2 v = stats[b * 32 + t]; smu[t] = v.x; srs[t] = v.y; }
    sw[t] = gnw[t]; sw[t + 256] = gnw[t + 256];
    sbv[t] = gnb[t]; sbv[t + 256] = gnb[t + 256];
    __syncthreads();
    #pragma unroll 4
    for (int it = 0; it < 32; ++it) {
        int id = it * 256 + t;
        int c = id >> 4, f4 = id & 15;
        float4 v = ((const float4*)x)[(size_t)(b * 512 + c) * 256 + (s0 >> 2) + f4];
        int g = c >> 4;
        float mu = smu[g], r = srs[g], wgt = sw[c], bia = sbv[c];
        hs[f4 * 4 + 0][c] = f2bf((v.x - mu) * r * wgt + bia);
        hs[f4 * 4 + 1][c] = f2bf((v.y - mu) * r * wgt + bia);
        hs[f4 * 4 + 2][c] = f2bf((v.z - mu) * r * wgt + bia);
        hs[f4 * 4 + 3][c] = f2bf((v.w - mu) * r * wgt + bia);
    }
    __syncthreads();
    int lane = t & 63, wrow = t >> 6;
    #pragma unroll 4
    for (int it = 0; it < 16; ++it) {
        int s = it * 4 + wrow;
        float4 vv = *(const float4*)&hs[s][lane * 8];
        *((float4*)h + (size_t)(b * 1024 + s0 + s) * 64 + lane) = vv;
    }
}

// ---------------------------------------------------------------------------
// QKV GEMM: [32768 x 1536] = h[32768x512] @ Wqkv[1536x512]^T + bqkv
// Q: token-major, pre-scaled by 512^-0.5.
// K: per-(batch, 64-key tile) image [64 key][512 c], 16B blocks XOR-swizzled
//    by (key&7) along c  -> flash stages it contiguously, reads conflict-low.
// V: per-tile image [512 c][64 key], 16B blocks XOR-swizzled by (c&7) along k.
// ---------------------------------------------------------------------------
__global__ __launch_bounds__(256, 2) void gemm_qkv(
    const u16* __restrict__ h, const u16* __restrict__ Wqkv,
    const float* __restrict__ bqkv,
    u16* __restrict__ Qo, u16* __restrict__ Ko, u16* __restrict__ Vo) {
    int n0 = blockIdx.x * 128, m0 = blockIdx.y * 128;
    __shared__ alignas(16) u16 As[128][32];
    __shared__ alignas(16) u16 Bs[128][32];
    __shared__ alignas(16) u16 Tr[128][136];
    int t = threadIdx.x, w = t >> 6, l = t & 63;
    int lane16 = l & 15, quad = l >> 4;
    int wm = w & 1, wn = w >> 1;
    v4f acc[4][4] = {};
    for (int k0 = 0; k0 < 512; k0 += 32) {
        #pragma unroll
        for (int i = 0; i < 2; ++i) {
            int id = i * 256 + t, row = id >> 2, c16 = id & 3;
            gl2lds(&h[(size_t)(m0 + row) * 512 + k0 + c16 * 8], &As[row][c16 * 8]);
            gl2lds(&Wqkv[(size_t)(n0 + row) * 512 + k0 + c16 * 8], &Bs[row][c16 * 8]);
        }
        __syncthreads();
        v8s af[4], bf[4];
        #pragma unroll
        for (int i = 0; i < 4; ++i)
            af[i] = *(const v8s*)&As[wm * 64 + i * 16 + lane16][quad * 8];
        #pragma unroll
        for (int j = 0; j < 4; ++j)
            bf[j] = *(const v8s*)&Bs[wn * 64 + j * 16 + lane16][quad * 8];
        #pragma unroll
        for (int i = 0; i < 4; ++i)
            #pragma unroll
            for (int j = 0; j < 4; ++j)
                acc[i][j] = MFMA16(af[i], bf[j], acc[i][j]);
        __syncthreads();
    }
    float bias[4];
    #pragma unroll
    for (int j = 0; j < 4; ++j) bias[j] = bqkv[n0 + wn * 64 + j * 16 + lane16];

    if (n0 < 1024) {
        // Q or K: stage [token][channel] tile in LDS
        const float qscale = (n0 < 512) ? 0.04419417382415922f : 1.0f;
        #pragma unroll
        for (int i = 0; i < 4; ++i)
            #pragma unroll
            for (int j = 0; j < 4; ++j)
                #pragma unroll
                for (int r = 0; r < 4; ++r) {
                    int row = wm * 64 + i * 16 + quad * 4 + r;
                    int col = wn * 64 + j * 16 + lane16;
                    Tr[row][col] = f2bf((acc[i][j][r] + bias[j]) * qscale);
                }
        __syncthreads();
        if (n0 < 512) {
            #pragma unroll
            for (int it = 0; it < 8; ++it) {
                int id = it * 256 + t, row = id >> 4, ch = id & 15;
                *(float4*)&Qo[(size_t)(m0 + row) * 512 + n0 + ch * 8] =
                    *(const float4*)&Tr[row][ch * 8];
            }
        } else {
            int c0 = n0 - 512, b = m0 >> 10, sb = m0 & 1023;
            #pragma unroll
            for (int it = 0; it < 8; ++it) {
                int id = it * 256 + t, row = id >> 4, ch = id & 15;
                int s = sb + row, kt = s >> 6, key = s & 63;
                int kb = ((c0 + ch * 8) >> 3) ^ (key & 7);   // XOR swizzle
                *(float4*)&Ko[((size_t)(b * 16 + kt)) * 32768 + key * 512 + kb * 8] =
                    *(const float4*)&Tr[row][ch * 8];
            }
        }
    } else {
        // V: stage TRANSPOSED [channel][token] in LDS
        #pragma unroll
        for (int i = 0; i < 4; ++i)
            #pragma unroll
            for (int j = 0; j < 4; ++j)
                #pragma unroll
                for (int r = 0; r < 4; ++r) {
                    int row = wm * 64 + i * 16 + quad * 4 + r;
                    int col = wn * 64 + j * 16 + lane16;
                    Tr[col][row] = f2bf(acc[i][j][r] + bias[j]);
                }
        __syncthreads();
        int c0 = n0 - 1024, b = m0 >> 10, sb = m0 & 1023;
        #pragma unroll
        for (int it = 0; it < 8; ++it) {
            int id = it * 256 + t, c = id >> 4, ch = id & 15;
            int s = sb + ch * 8, kt = s >> 6, key = s & 63;
            int kb = (key >> 3) ^ (c & 7);                    // XOR swizzle
            *(float4*)&Vo[((size_t)(b * 16 + kt)) * 32768 + (size_t)(c0 + c) * 64 + kb * 8] =
                *(const float4*)&Tr[c][ch * 8];
        }
    }
}

// ---------------------------------------------------------------------------
// Flash attention v2: block = 64 queries, 512 thr / 8 waves.
// waves = 4 q-subtiles(16q) x 2 key-halves; 64-key K-tiles; each wave
// contracts PV over ITS 32 keys only (one K=32 MFMA chunk) -> half the LDS
// B-frag traffic per key vs v1. Partial O / l merged once at the end.
// 3-phase pipeline: stage-K overlaps PV, stage-V overlaps next QK.
// ---------------------------------------------------------------------------
__global__ __launch_bounds__(512, 2) void flash_attn(
    const u16* __restrict__ Q, const u16* __restrict__ Kt,
    const u16* __restrict__ Vt, u16* __restrict__ O) {
    int idx = blockIdx.x;
    int xcd = idx & 7, j = idx >> 3;          // 64 blocks per XCD slot
    int bz = xcd * 4 + (j >> 4);              // batch: 4 per XCD
    int qb = j & 15;                          // 64-query block 0..15

    __shared__ alignas(16) char lds[141312];
    u16* Ks  = (u16*)lds;                     // [64 key][512 c] swizzled, 64 KB
    u16* Vts = (u16*)(lds + 65536);           // [512 c][64 key] swizzled, 64 KB
    u16* Pw  = (u16*)(lds + 131072);          // per-wave [16][40]

    int t = threadIdx.x, w = t >> 6, l = t & 63;
    int lane16 = l & 15, quad = l >> 4;
    int qs = w & 3, kh = w >> 2;              // q-subtile, key-half
    int swz = lane16 & 7;                     // per-lane XOR-swizzle key

    const u16* Kb = Kt + (size_t)bz * 16 * 32768;
    const u16* Vb = Vt + (size_t)bz * 16 * 32768;
    u16* PwW = Pw + w * 640;

    // Q fragments: 16 q rows = qb*64 + qs*16 + lane16 (scale pre-folded)
    int qtok = bz * 1024 + qb * 64 + qs * 16 + lane16;
    v8s qf[16];
    #pragma unroll
    for (int kk = 0; kk < 16; ++kk)
        qf[kk] = *(const v8s*)&Q[(size_t)qtok * 512 + kk * 32 + quad * 8];

    v4f lis = {0.f, 0.f, 0.f, 0.f};
    v4f ao[32] = {};

    // stage tile 0 (64 chunks of 1KB each for K and V)
    #pragma unroll
    for (int c = 0; c < 8; ++c) {
        gl2lds(&Kb[(c * 8 + w) * 512 + l * 8], &Ks[(c * 8 + w) * 512 + l * 8]);
        gl2lds(&Vb[(c * 8 + w) * 512 + l * 8], &Vts[(c * 8 + w) * 512 + l * 8]);
    }

    for (int kt = 0; kt < 16; ++kt) {
        __syncthreads();   // b0/b2': K(kt),V(kt) staged & all waves past prior reads

        // ---- QK on this wave's 32 keys (rows kh*32 .. kh*32+31) ----
        v4f s0 = {}, s1 = {};
        #pragma unroll
        for (int kk = 0; kk < 16; ++kk) {
            int kbsw = ((kk * 4 + quad) ^ swz) * 8;
            v8s b0 = *(const v8s*)&Ks[(kh * 32 + lane16) * 512 + kbsw];
            v8s b1 = *(const v8s*)&Ks[(kh * 32 + 16 + lane16) * 512 + kbsw];
            s0 = MFMA16(qf[kk], b0, s0);
            s1 = MFMA16(qf[kk], b1, s1);
        }
        #pragma unroll
        for (int r = 0; r < 4; ++r) {
            float p0 = __expf(s0[r]), p1 = __expf(s1[r]);
            lis[r] += p0 + p1;
            PwW[(quad * 4 + r) * 40 + lane16] = f2bf(p0);
            PwW[(quad * 4 + r) * 40 + 16 + lane16] = f2bf(p1);
        }

        __syncthreads();   // b1: all waves done reading Ks; drains V(kt)
        if (kt + 1 < 16) { // stage K(kt+1) -- overlaps PV below
            const u16* kn = Kb + (size_t)(kt + 1) * 32768;
            #pragma unroll
            for (int c = 0; c < 8; ++c)
                gl2lds(&kn[(c * 8 + w) * 512 + l * 8], &Ks[(c * 8 + w) * 512 + l * 8]);
        }

        // ---- PV: contraction over this wave's 32 keys (K=32 exactly) ----
        v8s pf = *(const v8s*)&PwW[lane16 * 40 + quad * 8];
        int vbsw = ((kh * 4 + quad) ^ swz) * 8;
        #pragma unroll
        for (int n = 0; n < 32; ++n) {
            v8s vf = *(const v8s*)&Vts[(n * 16 + lane16) * 64 + vbsw];
            ao[n] = MFMA16(pf, vf, ao[n]);
        }

        __syncthreads();   // b2: all waves done reading Vts; drains K(kt+1)
        if (kt + 1 < 16) { // stage V(kt+1) -- overlaps next QK
            const u16* vn = Vb + (size_t)(kt + 1) * 32768;
            #pragma unroll
            for (int c = 0; c < 8; ++c)
                gl2lds(&vn[(c * 8 + w) * 512 + l * 8], &Vts[(c * 8 + w) * 512 + l * 8]);
        }
    }

    // ---- merge key-halves: kh=1 waves export partial O and l via LDS ----
    __syncthreads();
    float* mrg = (float*)(lds) + qs * 8448;   // 33792 B per q-subtile slot
    if (kh == 1) {
        #pragma unroll
        for (int n = 0; n < 32; ++n)
            *(v4f*)&mrg[n * 256 + l * 4] = ao[n];
        *(v4f*)&mrg[8192 + l * 4] = lis;
    }
    __syncthreads();
    if (kh == 0) {
        #pragma unroll
        for (int n = 0; n < 32; ++n) {
            v4f p = *(const v4f*)&mrg[n * 256 + l * 4];
            ao[n][0] += p[0]; ao[n][1] += p[1]; ao[n][2] += p[2]; ao[n][3] += p[3];
        }
        v4f pl = *(const v4f*)&mrg[8192 + l * 4];
        float inv[4];
        #pragma unroll
        for (int r = 0; r < 4; ++r) {
            float s = lis[r] + pl[r];
            s += __shfl_xor(s, 1);
            s += __shfl_xor(s, 2);
            s += __shfl_xor(s, 4);
            s += __shfl_xor(s, 8);
            inv[r] = 1.0f / s;
        }
        int orow = bz * 1024 + qb * 64 + qs * 16 + quad * 4;
        #pragma unroll
        for (int n = 0; n < 32; ++n)
            #pragma unroll
            for (int r = 0; r < 4; ++r)
                O[(size_t)(orow + r) * 512 + n * 16 + lane16] = f2bf(ao[n][r] * inv[r]);
    }
}

// ---------------------------------------------------------------------------
// Proj GEMM + residual: out[b][c][token] = x + Wp @ O_b^T + bp
// ---------------------------------------------------------------------------
__global__ __launch_bounds__(256, 2) void gemm_proj(
    const u16* __restrict__ Wp, const u16* __restrict__ O,
    const float* __restrict__ x, const float* __restrict__ bp,
    float* __restrict__ out) {
    int n0 = blockIdx.x * 128, m0 = blockIdx.y * 128, b = blockIdx.z;
    __shared__ alignas(16) u16 As[128][32];
    __shared__ alignas(16) u16 Bs[128][32];
    int t = threadIdx.x, w = t >> 6, l = t & 63;
    int lane16 = l & 15, quad = l >> 4;
    int wm = w & 1, wn = w >> 1;
    v4f acc[4][4] = {};
    for (int k0 = 0; k0 < 512; k0 += 32) {
        #pragma unroll
        for (int i = 0; i < 2; ++i) {
            int id = i * 256 + t, row = id >> 2, c16 = id & 3;
            gl2lds(&Wp[(size_t)(m0 + row) * 512 + k0 + c16 * 8], &As[row][c16 * 8]);
            gl2lds(&O[(size_t)(b * 1024 + n0 + row) * 512 + k0 + c16 * 8], &Bs[row][c16 * 8]);
        }
        __syncthreads();
        v8s af[4], bf[4];
        #pragma unroll
        for (int i = 0; i < 4; ++i)
            af[i] = *(const v8s*)&As[wm * 64 + i * 16 + lane16][quad * 8];
        #pragma unroll
        for (int j = 0; j < 4; ++j)
            bf[j] = *(const v8s*)&Bs[wn * 64 + j * 16 + lane16][quad * 8];
        #pragma unroll
        for (int i = 0; i < 4; ++i)
            #pragma unroll
            for (int j = 0; j < 4; ++j)
                acc[i][j] = MFMA16(af[i], bf[j], acc[i][j]);
        __syncthreads();
    }
    #pragma unroll
    for (int i = 0; i < 4; ++i) {
        #pragma unroll
        for (int r = 0; r < 4; ++r) {
            int row = wm * 64 + i * 16 + quad * 4 + r;
            float bia = bp[m0 + row];
            #pragma unroll
            for (int j = 0; j < 4; ++j) {
                int col = wn * 64 + j * 16 + lane16;
                size_t idx = (size_t)(b * 512 + m0 + row) * 1024 + n0 + col;
                out[idx] = acc[i][j][r] + bia + x[idx];
            }
        }
    }
}

// ---------------------------------------------------------------------------
extern "C" void kernel_launch(void* const* d_in, const int* in_sizes, int n_in,
                              void* d_out, int out_size, void* d_ws, size_t ws_size,
                              hipStream_t stream) {
    (void)in_sizes; (void)n_in; (void)out_size; (void)ws_size;
    const float* x   = (const float*)d_in[0];
    const float* gnw = (const float*)d_in[1];
    const float* gnb = (const float*)d_in[2];
    const float* wq  = (const float*)d_in[3];
    const float* bq  = (const float*)d_in[4];
    const float* wk  = (const float*)d_in[5];
    const float* bk  = (const float*)d_in[6];
    const float* wv  = (const float*)d_in[7];
    const float* bv  = (const float*)d_in[8];
    const float* wp  = (const float*)d_in[9];
    const float* bp  = (const float*)d_in[10];
    float* out = (float*)d_out;

    char* ws = (char*)d_ws;
    u16*    Wqkv  = (u16*)(ws + 0);                       // 1.5 MB
    u16*    Wp    = (u16*)(ws + 1572864);                 // 0.5 MB
    float*  bqkv  = (float*)(ws + 2097152);               // 6 KB
    float2* stats = (float2*)(ws + 2105344);              // 8 KB
    u16*    h     = (u16*)(ws + 4194304ULL);              // 32 MB (reused as O)
    u16*    Qb    = (u16*)(ws + 4194304ULL + 33554432ULL);        // 32 MB
    u16*    Kb    = (u16*)(ws + 4194304ULL + 2ULL * 33554432ULL); // 32 MB tiled/swizzled
    u16*    Vb    = (u16*)(ws + 4194304ULL + 3ULL * 33554432ULL); // 32 MB tiled/swizzled

    prep_kernel<<<4096, 256, 0, stream>>>(wq, wk, wv, wp, bq, bk, bv, Wqkv, Wp, bqkv);
    gn_stats<<<dim3(32, 32), 256, 0, stream>>>(x, stats);
    gn_apply<<<dim3(16, 32), 256, 0, stream>>>(x, stats, gnw, gnb, h);
    gemm_qkv<<<dim3(12, 256), 256, 0, stream>>>(h, Wqkv, bqkv, Qb, Kb, Vb);
    flash_attn<<<512, 512, 0, stream>>>(Qb, Kb, Vb, h /* -> O */);
    gemm_proj<<<dim3(8, 4, 32), 256, 0, stream>>>(Wp, h /* O */, x, bp, out);
}

// Round 5
// 356.886 us; speedup vs baseline: 1.0571x; 1.0571x over previous
//
#include <hip/hip_runtime.h>

typedef unsigned short u16;
typedef unsigned int u32;
typedef short v8s __attribute__((ext_vector_type(8)));
typedef float v4f __attribute__((ext_vector_type(4)));
typedef float v16f __attribute__((ext_vector_type(16)));

#define MFMA16(a, b, c) __builtin_amdgcn_mfma_f32_16x16x32_bf16((a), (b), (c), 0, 0, 0)
#define MFMA32(a, b, c) __builtin_amdgcn_mfma_f32_32x32x16_bf16((a), (b), (c), 0, 0, 0)

static __device__ __forceinline__ u16 f2bf(float f) {
    u32 u = __float_as_uint(f);
    u += 0x7fffu + ((u >> 16) & 1u);   // RNE
    return (u16)(u >> 16);
}

// async global->LDS, 16B per lane. LDS dest must be wave-uniform base + lane*16.
static __device__ __forceinline__ void gl2lds(const u16* g, u16* l) {
    __builtin_amdgcn_global_load_lds(
        (const __attribute__((address_space(1))) void*)g,
        (__attribute__((address_space(3))) void*)l, 16, 0, 0);
}

// ---------------------------------------------------------------------------
// prep: fp32 weights -> bf16 (Wqkv packed [1536][512], Wp [512][512]), bias pack
// ---------------------------------------------------------------------------
__global__ __launch_bounds__(256) void prep_kernel(
    const float* __restrict__ wq, const float* __restrict__ wk,
    const float* __restrict__ wv, const float* __restrict__ wp,
    const float* __restrict__ bq, const float* __restrict__ bk,
    const float* __restrict__ bv,
    u16* __restrict__ Wqkv, u16* __restrict__ Wp, float* __restrict__ bqkv) {
    int id = blockIdx.x * 256 + threadIdx.x;   // 0 .. 1048575
    float v;
    if (id < 262144)       v = wq[id];
    else if (id < 524288)  v = wk[id - 262144];
    else if (id < 786432)  v = wv[id - 524288];
    else                   v = wp[id - 786432];
    if (id < 786432) Wqkv[id] = f2bf(v);
    else             Wp[id - 786432] = f2bf(v);
    if (id < 1536) {
        float b = (id < 512) ? bq[id] : (id < 1024 ? bk[id - 512] : bv[id - 1024]);
        bqkv[id] = b;
    }
}

// ---------------------------------------------------------------------------
// GroupNorm pass 1: per (b,g) mean & rsigma over 16 ch x 1024 spatial
// ---------------------------------------------------------------------------
__global__ __launch_bounds__(256) void gn_stats(const float* __restrict__ x,
                                                float2* __restrict__ stats) {
    int g = blockIdx.x, b = blockIdx.y;
    const float4* x4 = (const float4*)x + (size_t)(b * 512 + g * 16) * 256;
    float s = 0.f, s2 = 0.f;
    for (int i = threadIdx.x; i < 4096; i += 256) {
        float4 v = x4[i];
        s  += v.x + v.y + v.z + v.w;
        s2 += v.x * v.x + v.y * v.y + v.z * v.z + v.w * v.w;
    }
    #pragma unroll
    for (int d = 1; d < 64; d <<= 1) { s += __shfl_xor(s, d); s2 += __shfl_xor(s2, d); }
    __shared__ float red1[4], red2[4];
    int w = threadIdx.x >> 6;
    if ((threadIdx.x & 63) == 0) { red1[w] = s; red2[w] = s2; }
    __syncthreads();
    if (threadIdx.x == 0) {
        s = red1[0] + red1[1] + red1[2] + red1[3];
        s2 = red2[0] + red2[1] + red2[2] + red2[3];
        float mu = s * (1.0f / 16384.0f);
        float var = s2 * (1.0f / 16384.0f) - mu * mu;
        stats[b * 32 + g] = make_float2(mu, rsqrtf(var + 1e-5f));
    }
}

// ---------------------------------------------------------------------------
// GroupNorm pass 2 + transpose: x[b,c,s] fp32 -> h[b*1024+s][c] bf16 (token-major)
// ---------------------------------------------------------------------------
__global__ __launch_bounds__(256) void gn_apply(
    const float* __restrict__ x, const float2* __restrict__ stats,
    const float* __restrict__ gnw, const float* __restrict__ gnb,
    u16* __restrict__ h) {
    int st = blockIdx.x, b = blockIdx.y;
    int s0 = st * 64;
    __shared__ float smu[32], srs[32], sw[512], sbv[512];
    __shared__ alignas(16) u16 hs[64][520];
    int t = threadIdx.x;
    if (t < 32) { float2 v = stats[b * 32 + t]; smu[t] = v.x; srs[t] = v.y; }
    sw[t] = gnw[t]; sw[t + 256] = gnw[t + 256];
    sbv[t] = gnb[t]; sbv[t + 256] = gnb[t + 256];
    __syncthreads();
    #pragma unroll 4
    for (int it = 0; it < 32; ++it) {
        int id = it * 256 + t;
        int c = id >> 4, f4 = id & 15;
        float4 v = ((const float4*)x)[(size_t)(b * 512 + c) * 256 + (s0 >> 2) + f4];
        int g = c >> 4;
        float mu = smu[g], r = srs[g], wgt = sw[c], bia = sbv[c];
        hs[f4 * 4 + 0][c] = f2bf((v.x - mu) * r * wgt + bia);
        hs[f4 * 4 + 1][c] = f2bf((v.y - mu) * r * wgt + bia);
        hs[f4 * 4 + 2][c] = f2bf((v.z - mu) * r * wgt + bia);
        hs[f4 * 4 + 3][c] = f2bf((v.w - mu) * r * wgt + bia);
    }
    __syncthreads();
    int lane = t & 63, wrow = t >> 6;
    #pragma unroll 4
    for (int it = 0; it < 16; ++it) {
        int s = it * 4 + wrow;
        float4 vv = *(const float4*)&hs[s][lane * 8];
        *((float4*)h + (size_t)(b * 1024 + s0 + s) * 64 + lane) = vv;
    }
}

// ---------------------------------------------------------------------------
// QKV GEMM. Q: token-major, pre-scaled by 512^-0.5.
// K: per-(batch, 32-key tile) image [32 key][512 ch]; 16B blocks (64/row)
//    XOR-swizzled by (key&7).
// V: per-tile image [512 ch][32 key]; 16B blocks (4/row) XOR-swizzled by
//    ((ch>>1)&3). Both images copied verbatim to LDS by flash_attn.
// ---------------------------------------------------------------------------
__global__ __launch_bounds__(256, 2) void gemm_qkv(
    const u16* __restrict__ h, const u16* __restrict__ Wqkv,
    const float* __restrict__ bqkv,
    u16* __restrict__ Qo, u16* __restrict__ Ko, u16* __restrict__ Vo) {
    int n0 = blockIdx.x * 128, m0 = blockIdx.y * 128;
    __shared__ alignas(16) u16 As[128][32];
    __shared__ alignas(16) u16 Bs[128][32];
    __shared__ alignas(16) u16 Tr[128][136];
    int t = threadIdx.x, w = t >> 6, l = t & 63;
    int lane16 = l & 15, quad = l >> 4;
    int wm = w & 1, wn = w >> 1;
    v4f acc[4][4] = {};
    for (int k0 = 0; k0 < 512; k0 += 32) {
        #pragma unroll
        for (int i = 0; i < 2; ++i) {
            int id = i * 256 + t, row = id >> 2, c16 = id & 3;
            gl2lds(&h[(size_t)(m0 + row) * 512 + k0 + c16 * 8], &As[row][c16 * 8]);
            gl2lds(&Wqkv[(size_t)(n0 + row) * 512 + k0 + c16 * 8], &Bs[row][c16 * 8]);
        }
        __syncthreads();
        v8s af[4], bf[4];
        #pragma unroll
        for (int i = 0; i < 4; ++i)
            af[i] = *(const v8s*)&As[wm * 64 + i * 16 + lane16][quad * 8];
        #pragma unroll
        for (int j = 0; j < 4; ++j)
            bf[j] = *(const v8s*)&Bs[wn * 64 + j * 16 + lane16][quad * 8];
        #pragma unroll
        for (int i = 0; i < 4; ++i)
            #pragma unroll
            for (int j = 0; j < 4; ++j)
                acc[i][j] = MFMA16(af[i], bf[j], acc[i][j]);
        __syncthreads();
    }
    float bias[4];
    #pragma unroll
    for (int j = 0; j < 4; ++j) bias[j] = bqkv[n0 + wn * 64 + j * 16 + lane16];

    if (n0 < 1024) {
        // Q or K: stage [token][channel] tile in LDS
        const float qscale = (n0 < 512) ? 0.04419417382415922f : 1.0f;
        #pragma unroll
        for (int i = 0; i < 4; ++i)
            #pragma unroll
            for (int j = 0; j < 4; ++j)
                #pragma unroll
                for (int r = 0; r < 4; ++r) {
                    int row = wm * 64 + i * 16 + quad * 4 + r;
                    int col = wn * 64 + j * 16 + lane16;
                    Tr[row][col] = f2bf((acc[i][j][r] + bias[j]) * qscale);
                }
        __syncthreads();
        if (n0 < 512) {
            #pragma unroll
            for (int it = 0; it < 8; ++it) {
                int id = it * 256 + t, row = id >> 4, ch = id & 15;
                *(float4*)&Qo[(size_t)(m0 + row) * 512 + n0 + ch * 8] =
                    *(const float4*)&Tr[row][ch * 8];
            }
        } else {
            int c0 = n0 - 512, b = m0 >> 10, sb = m0 & 1023;
            #pragma unroll
            for (int it = 0; it < 8; ++it) {
                int id = it * 256 + t, row = id >> 4, ch = id & 15;
                int s = sb + row, kt = s >> 5, key = s & 31;
                int kb = ((c0 + ch * 8) >> 3) ^ (key & 7);   // XOR swizzle (64 blocks/row)
                *(float4*)&Ko[((size_t)(b * 32 + kt)) * 16384 + key * 512 + kb * 8] =
                    *(const float4*)&Tr[row][ch * 8];
            }
        }
    } else {
        // V: stage TRANSPOSED [channel][token] in LDS
        #pragma unroll
        for (int i = 0; i < 4; ++i)
            #pragma unroll
            for (int j = 0; j < 4; ++j)
                #pragma unroll
                for (int r = 0; r < 4; ++r) {
                    int row = wm * 64 + i * 16 + quad * 4 + r;
                    int col = wn * 64 + j * 16 + lane16;
                    Tr[col][row] = f2bf(acc[i][j][r] + bias[j]);
                }
        __syncthreads();
        int c0 = n0 - 1024, b = m0 >> 10, sb = m0 & 1023;
        #pragma unroll
        for (int it = 0; it < 8; ++it) {
            int id = it * 256 + t, c = id >> 4, ch8 = id & 15;
            int key0 = sb + ch8 * 8;                  // 8 consecutive keys
            int kt = key0 >> 5;
            int kblk = (key0 >> 3) & 3;               // block within 4-block row
            int ch = c0 + c;
            int swz = (ch >> 1) & 3;
            *(float4*)&Vo[((size_t)(b * 32 + kt)) * 16384 + (size_t)ch * 32 +
                          ((kblk ^ swz) * 8)] =
                *(const float4*)&Tr[c][ch8 * 8];
        }
    }
}

// ---------------------------------------------------------------------------
// Flash attention v3: producer/consumer wave specialization.
// Block = 64 queries, 512 thr / 8 waves, full 1024 keys in 32-key tiles.
//  Waves 0-3 (producers, (qs,kh)): QK for 32q x 16 keys via 16x16x32, Q held
//    as TWO A-frag sets (128 VGPR) -> each K B-read feeds 2 MFMAs. exp() ->
//    P image (double-buffered) + per-row l partials.
//  Waves 4-7 (consumers, (qs2,chh)): PV via 32x32x16: O^T[256ch x 32q],
//    A=V^T from LDS (1 read / 16384-FLOP MFMA), B=P^T read once per key-16
//    chunk and reused across 8 ch-blocks. Consumers lag producers by 1 tile.
// One barrier per tile; K/V/P double-buffered; stages issued right after the
// barrier fly under the whole compute phase. All LDS patterns bank-uniform.
// ---------------------------------------------------------------------------
__global__ __launch_bounds__(512, 2) void flash_attn(
    const u16* __restrict__ Q, const u16* __restrict__ Kt,
    const u16* __restrict__ Vt, u16* __restrict__ O) {
    int idx = blockIdx.x;
    int xcd = idx & 7, j = idx >> 3;          // XCD-aware: 4 batches per XCD
    int bz = xcd * 4 + (j >> 4);
    int qb = j & 15;                          // 64-query block

    __shared__ alignas(16) char lds[139776];
    u16*   KsB  = (u16*)lds;                  // [2][32][512]  64 KB
    u16*   VsB  = (u16*)(lds + 65536);        // [2][512][32]  64 KB
    u16*   Pb   = (u16*)(lds + 131072);       // [2][64][32]    8 KB
    float* lsum = (float*)(lds + 139264);     // [2][64]      0.5 KB

    int t = threadIdx.x, w = t >> 6, l = t & 63;
    int lane16 = l & 15, quad = l >> 4;
    int s5 = l >> 5, l31 = l & 31;

    const u16* Kb = Kt + (size_t)bz * 32 * 16384;
    const u16* Vb = Vt + (size_t)bz * 32 * 16384;

    // prologue: stage K tile 0 (each wave copies 4 KB of the 32 KB tile)
    #pragma unroll
    for (int c = 0; c < 4; ++c) {
        int ch = w * 4 + c;
        gl2lds(&Kb[ch * 512 + l * 8], &KsB[ch * 512 + l * 8]);
    }
    __syncthreads();

    if (w < 4) {
        // ================= PRODUCER =================
        int qs = w & 1, kh = w >> 1;
        int qrow = bz * 1024 + qb * 64 + qs * 32 + lane16;
        v8s qf0[16], qf1[16];
        #pragma unroll
        for (int kk = 0; kk < 16; ++kk) {
            qf0[kk] = *(const v8s*)&Q[(size_t)qrow * 512 + kk * 32 + quad * 8];
            qf1[kk] = *(const v8s*)&Q[(size_t)(qrow + 16) * 512 + kk * 32 + quad * 8];
        }
        v4f li0 = {}, li1 = {};
        int key = kh * 16 + lane16;
        int krowoff = key * 512;
        int kswz = lane16 & 7;

        for (int kt = 0; kt <= 32; ++kt) {
            if (kt + 1 < 32) {
                u16* kd = KsB + ((kt + 1) & 1) * 16384;
                const u16* ks = Kb + (size_t)(kt + 1) * 16384;
                #pragma unroll
                for (int c = 0; c < 4; ++c) {
                    int ch = w * 4 + c;
                    gl2lds(&ks[ch * 512 + l * 8], &kd[ch * 512 + l * 8]);
                }
            }
            if (kt < 32) {
                u16* vd = VsB + (kt & 1) * 16384;
                const u16* vs = Vb + (size_t)kt * 16384;
                #pragma unroll
                for (int c = 0; c < 4; ++c) {
                    int ch = w * 4 + c;
                    gl2lds(&vs[ch * 512 + l * 8], &vd[ch * 512 + l * 8]);
                }
                const u16* KsT = KsB + (kt & 1) * 16384;
                u16* Pt = Pb + (kt & 1) * 2048;
                v4f sA = {}, sB = {};
                #pragma unroll
                for (int kk = 0; kk < 16; ++kk) {
                    v8s b = *(const v8s*)&KsT[krowoff + (((kk * 4 + quad) ^ kswz) * 8)];
                    sA = MFMA16(qf0[kk], b, sA);
                    sB = MFMA16(qf1[kk], b, sB);
                }
                #pragma unroll
                for (int r = 0; r < 4; ++r) {
                    float p0 = __expf(sA[r]), p1 = __expf(sB[r]);
                    li0[r] += p0; li1[r] += p1;
                    int q0 = qs * 32 + quad * 4 + r, q1 = q0 + 16;
                    Pt[q0 * 32 + (((key >> 3) ^ ((q0 >> 1) & 3)) * 8) + (key & 7)] = f2bf(p0);
                    Pt[q1 * 32 + (((key >> 3) ^ ((q1 >> 1) & 3)) * 8) + (key & 7)] = f2bf(p1);
                }
            }
            __syncthreads();
        }
        // reduce l over the 16 keys of this wave, publish per-kh partials
        #pragma unroll
        for (int r = 0; r < 4; ++r) {
            float a = li0[r], b = li1[r];
            a += __shfl_xor(a, 1); a += __shfl_xor(a, 2);
            a += __shfl_xor(a, 4); a += __shfl_xor(a, 8);
            b += __shfl_xor(b, 1); b += __shfl_xor(b, 2);
            b += __shfl_xor(b, 4); b += __shfl_xor(b, 8);
            if (lane16 == 0) {
                lsum[kh * 64 + qs * 32 + quad * 4 + r] = a;
                lsum[kh * 64 + qs * 32 + 16 + quad * 4 + r] = b;
            }
        }
        __syncthreads();
    } else {
        // ================= CONSUMER =================
        int cw = w - 4, qs2 = cw & 1, chh = cw >> 1;
        v16f acc[8] = {};
        int q = qs2 * 32 + l31;
        int pswz = (q >> 1) & 3;

        for (int kt = 0; kt <= 32; ++kt) {
            if (kt + 1 < 32) {
                u16* kd = KsB + ((kt + 1) & 1) * 16384;
                const u16* ks = Kb + (size_t)(kt + 1) * 16384;
                #pragma unroll
                for (int c = 0; c < 4; ++c) {
                    int ch = w * 4 + c;
                    gl2lds(&ks[ch * 512 + l * 8], &kd[ch * 512 + l * 8]);
                }
            }
            if (kt < 32) {
                u16* vd = VsB + (kt & 1) * 16384;
                const u16* vs = Vb + (size_t)kt * 16384;
                #pragma unroll
                for (int c = 0; c < 4; ++c) {
                    int ch = w * 4 + c;
                    gl2lds(&vs[ch * 512 + l * 8], &vd[ch * 512 + l * 8]);
                }
            }
            if (kt >= 1) {
                int kp = (kt - 1) & 1;
                const u16* Pt  = Pb + kp * 2048;
                const u16* VsT = VsB + kp * 16384;
                #pragma unroll
                for (int kc = 0; kc < 2; ++kc) {
                    v8s pb = *(const v8s*)&Pt[q * 32 + (((kc * 2 + s5) ^ pswz) * 8)];
                    #pragma unroll
                    for (int chb = 0; chb < 8; ++chb) {
                        int ch = chh * 256 + chb * 32 + l31;
                        v8s vf = *(const v8s*)&VsT[ch * 32 +
                                                   (((kc * 2 + s5) ^ ((ch >> 1) & 3)) * 8)];
                        acc[chb] = MFMA32(vf, pb, acc[chb]);
                    }
                }
            }
            __syncthreads();
        }
        __syncthreads();   // wait for lsum
        float inv = 1.0f / (lsum[q] + lsum[64 + q]);
        int token = bz * 1024 + qb * 64 + q;
        #pragma unroll
        for (int chb = 0; chb < 8; ++chb) {
            #pragma unroll
            for (int rg = 0; rg < 4; ++rg) {
                int ch0 = chh * 256 + chb * 32 + rg * 8 + s5 * 4;
                u16 o4[4];
                #pragma unroll
                for (int i = 0; i < 4; ++i) o4[i] = f2bf(acc[chb][rg * 4 + i] * inv);
                *(uint2*)&O[(size_t)token * 512 + ch0] = *(const uint2*)o4;
            }
        }
    }
}

// ---------------------------------------------------------------------------
// Proj GEMM + residual: out[b][c][token] = x + Wp @ O_b^T + bp
// ---------------------------------------------------------------------------
__global__ __launch_bounds__(256, 2) void gemm_proj(
    const u16* __restrict__ Wp, const u16* __restrict__ O,
    const float* __restrict__ x, const float* __restrict__ bp,
    float* __restrict__ out) {
    int n0 = blockIdx.x * 128, m0 = blockIdx.y * 128, b = blockIdx.z;
    __shared__ alignas(16) u16 As[128][32];
    __shared__ alignas(16) u16 Bs[128][32];
    int t = threadIdx.x, w = t >> 6, l = t & 63;
    int lane16 = l & 15, quad = l >> 4;
    int wm = w & 1, wn = w >> 1;
    v4f acc[4][4] = {};
    for (int k0 = 0; k0 < 512; k0 += 32) {
        #pragma unroll
        for (int i = 0; i < 2; ++i) {
            int id = i * 256 + t, row = id >> 2, c16 = id & 3;
            gl2lds(&Wp[(size_t)(m0 + row) * 512 + k0 + c16 * 8], &As[row][c16 * 8]);
            gl2lds(&O[(size_t)(b * 1024 + n0 + row) * 512 + k0 + c16 * 8], &Bs[row][c16 * 8]);
        }
        __syncthreads();
        v8s af[4], bf[4];
        #pragma unroll
        for (int i = 0; i < 4; ++i)
            af[i] = *(const v8s*)&As[wm * 64 + i * 16 + lane16][quad * 8];
        #pragma unroll
        for (int j = 0; j < 4; ++j)
            bf[j] = *(const v8s*)&Bs[wn * 64 + j * 16 + lane16][quad * 8];
        #pragma unroll
        for (int i = 0; i < 4; ++i)
            #pragma unroll
            for (int j = 0; j < 4; ++j)
                acc[i][j] = MFMA16(af[i], bf[j], acc[i][j]);
        __syncthreads();
    }
    #pragma unroll
    for (int i = 0; i < 4; ++i) {
        #pragma unroll
        for (int r = 0; r < 4; ++r) {
            int row = wm * 64 + i * 16 + quad * 4 + r;
            float bia = bp[m0 + row];
            #pragma unroll
            for (int j = 0; j < 4; ++j) {
                int col = wn * 64 + j * 16 + lane16;
                size_t idx = (size_t)(b * 512 + m0 + row) * 1024 + n0 + col;
                out[idx] = acc[i][j][r] + bia + x[idx];
            }
        }
    }
}

// ---------------------------------------------------------------------------
extern "C" void kernel_launch(void* const* d_in, const int* in_sizes, int n_in,
                              void* d_out, int out_size, void* d_ws, size_t ws_size,
                              hipStream_t stream) {
    (void)in_sizes; (void)n_in; (void)out_size; (void)ws_size;
    const float* x   = (const float*)d_in[0];
    const float* gnw = (const float*)d_in[1];
    const float* gnb = (const float*)d_in[2];
    const float* wq  = (const float*)d_in[3];
    const float* bq  = (const float*)d_in[4];
    const float* wk  = (const float*)d_in[5];
    const float* bk  = (const float*)d_in[6];
    const float* wv  = (const float*)d_in[7];
    const float* bv  = (const float*)d_in[8];
    const float* wp  = (const float*)d_in[9];
    const float* bp  = (const float*)d_in[10];
    float* out = (float*)d_out;

    char* ws = (char*)d_ws;
    u16*    Wqkv  = (u16*)(ws + 0);                       // 1.5 MB
    u16*    Wp    = (u16*)(ws + 1572864);                 // 0.5 MB
    float*  bqkv  = (float*)(ws + 2097152);               // 6 KB
    float2* stats = (float2*)(ws + 2105344);              // 8 KB
    u16*    h     = (u16*)(ws + 4194304ULL);              // 32 MB (reused as O)
    u16*    Qb    = (u16*)(ws + 4194304ULL + 33554432ULL);        // 32 MB
    u16*    Kb    = (u16*)(ws + 4194304ULL + 2ULL * 33554432ULL); // 32 MB tiled/swizzled
    u16*    Vb    = (u16*)(ws + 4194304ULL + 3ULL * 33554432ULL); // 32 MB tiled/swizzled

    prep_kernel<<<4096, 256, 0, stream>>>(wq, wk, wv, wp, bq, bk, bv, Wqkv, Wp, bqkv);
    gn_stats<<<dim3(32, 32), 256, 0, stream>>>(x, stats);
    gn_apply<<<dim3(16, 32), 256, 0, stream>>>(x, stats, gnw, gnb, h);
    gemm_qkv<<<dim3(12, 256), 256, 0, stream>>>(h, Wqkv, bqkv, Qb, Kb, Vb);
    flash_attn<<<512, 512, 0, stream>>>(Qb, Kb, Vb, h /* -> O */);
    gemm_proj<<<dim3(8, 4, 32), 256, 0, stream>>>(Wp, h /* O */, x, bp, out);
}